// Round 8
// baseline (343.825 us; speedup 1.0000x reference)
//
#include <hip/hip_runtime.h>
#include <hip/hip_fp16.h>

// GRU (reset_after, inference) fused with dense head.
// B=1024 rows, T=512 steps, F=16 features, H=64 hidden.
// Round-8: TWO WAVES PER ROW (k-split), live set designed UNDER the 128-reg
// cap. R1-R7 evidence: the RA pins arch VGPRs at ~128-144 regardless of
// launch_bounds / waves_per_eu / asm "v" constraints, and parks the excess
// live set (~190) in AGPRs, paying v_accvgpr_read per use (~350 junk
// VALU cy/step, ~55% of issue). Fix by construction: split the k-reduction
// (and f-reduction) across 2 waves -> ~105 live regs/wave. Bonus: 2048
// waves = 2 waves/SIMD, mostly from DIFFERENT blocks -> uncorrelated
// stalls hide DS latency + gate chains.
//  - Each wave: 16x3 U-h2 (48 regs) + 4x3 W-h2 (12) + hp 16 + xp 4.
//  - Per-wave PRIVATE h copy in LDS (hbw[w]): written and re-read by the
//    same wave -> in-order DS pipe, no barrier for h.
//  - Cross-wave combine of (az, ar, axh, arh) partials: float4 in LDS,
//    double-buffered on t-parity, ONE barrier per step (round-0 scheme).
//  - fp16 weights via __builtin_amdgcn_fdot2 (v_dot2_f32_f16, fp32 acc).

#define T_ 512
#define F_ 16
#define H_ 64

typedef _Float16 half_t;
typedef _Float16 h2 __attribute__((ext_vector_type(2)));
typedef _Float16 h4 __attribute__((ext_vector_type(4)));
typedef _Float16 h8 __attribute__((ext_vector_type(8)));

__device__ __forceinline__ float fdot2f(h2 a, h2 b, float c) {
#if __has_builtin(__builtin_amdgcn_fdot2)
    return __builtin_amdgcn_fdot2(a, b, c, false);   // v_dot2_f32_f16
#else
    return fmaf((float)a.x, (float)b.x, fmaf((float)a.y, (float)b.y, c));
#endif
}

__device__ __forceinline__ float fast_rcp(float a) {
    return __builtin_amdgcn_rcpf(a);   // v_rcp_f32, ~1 ULP
}
__device__ __forceinline__ float sigm(float a) {
    return fast_rcp(1.0f + __expf(-a));
}
__device__ __forceinline__ float tanh_fast(float a) {
    // tanh(a) = 1 - 2/(exp(2a)+1); saturates correctly for large |a|
    return 1.0f - 2.0f * fast_rcp(__expf(2.0f * a) + 1.0f);
}

__global__ __launch_bounds__(128, 2) void gru_fused(
    const float* __restrict__ x, const float* __restrict__ W,
    const float* __restrict__ U, const float* __restrict__ b,
    const float* __restrict__ w1, const float* __restrict__ b1,
    const float* __restrict__ gamma_, const float* __restrict__ beta_,
    const float* __restrict__ mmean, const float* __restrict__ mvar,
    const float* __restrict__ w2, const float* __restrict__ b2,
    float* __restrict__ out)
{
    __shared__ __align__(16) half_t xs16[T_ * F_];      // 16 KB: x row fp16
    __shared__ __align__(16) half_t hbw[2][H_];         // per-WAVE h copies
    __shared__ __align__(16) float  comb[2 * 2 * 64 * 4]; // 4 KB: [par][w][lane][4]

    const int tid = threadIdx.x;
    const int j   = tid & 63;     // output hidden unit
    const int w   = tid >> 6;     // wave id 0/1
    const int row = blockIdx.x;

    // ---- stage x[row] into LDS as packed fp16 (16 iters, 128 threads) ----
    const float4* xr4 = (const float4*)(x + (size_t)row * (T_ * F_));
    #pragma unroll
    for (int i = 0; i < (T_ * F_ / 4) / 128; ++i) {   // 16 iters
        const float4 v = xr4[i * 128 + tid];
        h4 p = { (half_t)v.x, (half_t)v.y, (half_t)v.z, (half_t)v.w };
        ((h4*)xs16)[i * 128 + tid] = p;               // ds_write_b64
    }
    hbw[w][j] = (half_t)0.0f;                         // each wave's own h0

    // ---- this wave's k-half of U, packed h2 along k (48 regs) ----
    const int k0 = w * 32;
    h2 uz2[16], ur2[16], uh2[16];
    #pragma unroll
    for (int m = 0; m < 16; ++m) {
        const int k = k0 + 2 * m;
        uz2[m] = h2{ (half_t)U[k * 192 +       j], (half_t)U[(k + 1) * 192 +       j] };
        ur2[m] = h2{ (half_t)U[k * 192 +  64 + j], (half_t)U[(k + 1) * 192 +  64 + j] };
        uh2[m] = h2{ (half_t)U[k * 192 + 128 + j], (half_t)U[(k + 1) * 192 + 128 + j] };
    }
    // ---- this wave's f-half of W (12 regs) ----
    const int f0 = w * 8;
    h2 wz2[4], wr2[4], wh2[4];
    #pragma unroll
    for (int p = 0; p < 4; ++p) {
        const int f = f0 + 2 * p;
        wz2[p] = h2{ (half_t)W[f * 192 +       j], (half_t)W[(f + 1) * 192 +       j] };
        wr2[p] = h2{ (half_t)W[f * 192 +  64 + j], (half_t)W[(f + 1) * 192 +  64 + j] };
        wh2[p] = h2{ (half_t)W[f * 192 + 128 + j], (half_t)W[(f + 1) * 192 + 128 + j] };
    }
    // biases live only in wave 0's partials
    float bz = 0.f, brr = 0.f, bxh = 0.f, brh = 0.f;
    if (w == 0) {
        bz  = b[j]      + b[192 + j];   // bi_z + br_z
        brr = b[64 + j] + b[256 + j];   // bi_r + br_r
        bxh = b[128 + j];               // bi_h (x-part)
        brh = b[320 + j];               // br_h (rec-part)
    }

    __syncthreads();   // xs + hbw ready

    float h = 0.0f;
    for (int t = 0; t < T_; ++t) {
        // own-wave h slice: 4 uniform (broadcast) ds_read_b128 from the
        // wave's PRIVATE copy -> in-order DS, no barrier needed.
        h2 hp[16];
        #pragma unroll
        for (int q = 0; q < 4; ++q)
            *((h8*)&hp[4 * q]) = ((const h8*)&hbw[w][k0])[q];
        // this wave's x f-half: 1 uniform ds_read_b128
        h2 xp[4];
        *((h8*)&xp[0]) = *((const h8*)&xs16[t * F_ + f0]);

        float az0 = bz, ar0 = brr, axh = bxh, arh0 = brh;
        float az1 = 0.f, ar1 = 0.f, arh1 = 0.f;

        // x-part: 12 dot2 (independent of h)
        #pragma unroll
        for (int p = 0; p < 4; ++p) {
            az0 = fdot2f(xp[p], wz2[p], az0);
            ar0 = fdot2f(xp[p], wr2[p], ar0);
            axh = fdot2f(xp[p], wh2[p], axh);
        }
        // recurrence k-half: 48 dot2, 6 split chains
        #pragma unroll
        for (int m = 0; m < 16; m += 2) {
            az0  = fdot2f(hp[m],     uz2[m],     az0);
            ar0  = fdot2f(hp[m],     ur2[m],     ar0);
            arh0 = fdot2f(hp[m],     uh2[m],     arh0);
            az1  = fdot2f(hp[m + 1], uz2[m + 1], az1);
            ar1  = fdot2f(hp[m + 1], ur2[m + 1], ar1);
            arh1 = fdot2f(hp[m + 1], uh2[m + 1], arh1);
        }

        // cross-wave combine (double-buffered on parity; single barrier)
        const int par = t & 1;
        *(float4*)&comb[((par * 2 + w) * 64 + j) * 4] =
            make_float4(az0 + az1, ar0 + ar1, axh, arh0 + arh1);
        __syncthreads();
        const float4 o = *(const float4*)&comb[((par * 2 + (1 - w)) * 64 + j) * 4];

        // gates (computed redundantly in both waves -> both hold full h)
        const float z  = sigm(az0 + az1 + o.x);
        const float r  = sigm(ar0 + ar1 + o.y);
        const float hh = tanh_fast(fmaf(r, arh0 + arh1 + o.w, axh + o.z));
        h = fmaf(z, h - hh, hh);

        hbw[w][j] = (half_t)h;   // publish to OWN copy (ds_write_b16)
    }

    // ---- head: y = relu(h @ w1 + b1); BN(inference); out = y @ w2 + b2 ----
    float y = b1[j];
    const int hb2 = __float_as_int(h);
    #pragma unroll
    for (int k = 0; k < H_; ++k) {
        const float hk = __int_as_float(__builtin_amdgcn_readlane(hb2, k));
        y = fmaf(hk, w1[k * H_ + j], y);
    }
    y = fmaxf(y, 0.0f);
    y = fmaf((y - mmean[j]) * rsqrtf(mvar[j] + 1e-3f), gamma_[j], beta_[j]);

    float acc = y * w2[j];
    #pragma unroll
    for (int off = 32; off > 0; off >>= 1)
        acc += __shfl_down(acc, off, 64);
    if (tid == 0) out[row] = acc + b2[0];
}

extern "C" void kernel_launch(void* const* d_in, const int* in_sizes, int n_in,
                              void* d_out, int out_size, void* d_ws, size_t ws_size,
                              hipStream_t stream) {
    const float* x      = (const float*)d_in[0];
    const float* W      = (const float*)d_in[1];
    const float* U      = (const float*)d_in[2];
    const float* b      = (const float*)d_in[3];
    const float* w1     = (const float*)d_in[4];
    const float* b1     = (const float*)d_in[5];
    const float* gamma_ = (const float*)d_in[6];
    const float* beta_  = (const float*)d_in[7];
    const float* mmean  = (const float*)d_in[8];
    const float* mvar   = (const float*)d_in[9];
    const float* w2     = (const float*)d_in[10];
    const float* b2     = (const float*)d_in[11];
    float* out = (float*)d_out;

    const int B = in_sizes[0] / (T_ * F_);   // 1024
    gru_fused<<<B, 128, 0, stream>>>(x, W, U, b, w1, b1, gamma_, beta_,
                                     mmean, mvar, w2, b2, out);
}

// Round 9
// 304.789 us; speedup vs baseline: 1.1281x; 1.1281x over previous
//
#include <hip/hip_runtime.h>
#include <hip/hip_fp16.h>

// GRU (reset_after, inference) fused with dense head — MFMA edition.
// B=1024 rows, T=512 steps, F=16, H=64.
// R0-R8 post-mortems: ANY VALU-dot design pays ~36% AGPR-copy tax (the RA
// always parks register-resident weights in AGPRs; grants 84-144 arch VGPRs
// no matter what) + ~15% trans tax + barrier tax. Fix: make the stationary
// weights MFMA B-operands — MFMA reads AGPRs natively, so parking is FREE.
//
// Structure: 64 blocks x 256 threads; block owns 16 batch rows (MFMA M=16).
// Wave g owns output units 16g..16g+15: computes tiles z/r/rh for its units
// -> gates are wave-local, NO cross-wave combine. Per step, per wave:
//   9x mfma_f32_16x16x32_f16:
//     cz  = Wz-chunk(x) + Uz-chunk0(h) + Uz-chunk1(h)   (bias as C-init)
//     cr  = likewise; crh = Uh chunks (bias brh); cxh = Wh chunk (bias bxh)
//   x-projection is a zero-padded K=32 chunk (B rows 16..31 zeroed, so the
//   A garbage in lanes q>=2 multiplies zeros — harmless).
//   gates on 4 C elements/lane (rows m=4q+i), h_old in 4 registers.
//   h published fp16 to double-buffered hs[2][16][80] (one barrier/step).
// A fragment layout (m97-verified): lane l -> row m=l&15, k=8*(l>>4)+i
//   => h-part = 2 uniform-row ds_read_b128; x-part read from GLOBAL with
//   1-step register prefetch (no staging; 4 waves share addrs via L1).
// C/D layout (m89-verified): col=lane&15 (unit), row=4*(lane>>4)+reg.

#define T_ 512
#define F_ 16
#define H_ 64
#define ROWS_ 16
#define HSS 80   // hs row stride in fp16 (160 B: keeps 16-B alignment for b128)

typedef _Float16 half_t;
typedef _Float16 h8 __attribute__((ext_vector_type(8)));
typedef float f32x4 __attribute__((ext_vector_type(4)));

__device__ __forceinline__ float fast_rcp(float a) {
    return __builtin_amdgcn_rcpf(a);   // v_rcp_f32, ~1 ULP
}
__device__ __forceinline__ float sigm(float a) {
    return fast_rcp(1.0f + __expf(-a));
}
__device__ __forceinline__ float tanh_fast(float a) {
    // tanh(a) = 1 - 2/(exp(2a)+1); saturates correctly for large |a|
    return 1.0f - 2.0f * fast_rcp(__expf(2.0f * a) + 1.0f);
}

__global__ __launch_bounds__(256, 1) void gru_fused(
    const float* __restrict__ x, const float* __restrict__ W,
    const float* __restrict__ U, const float* __restrict__ b,
    const float* __restrict__ w1, const float* __restrict__ b1,
    const float* __restrict__ gamma_, const float* __restrict__ beta_,
    const float* __restrict__ mmean, const float* __restrict__ mvar,
    const float* __restrict__ w2, const float* __restrict__ b2,
    float* __restrict__ out)
{
    __shared__ __align__(16) half_t hs[2][ROWS_][HSS];   // 5 KB, dbuf on t
    __shared__ float hf[ROWS_][H_ + 4];                  // final h, fp32

    const int tid = threadIdx.x;
    const int w   = tid >> 6;     // wave 0..3 -> unit group
    const int l   = tid & 63;
    const int c   = l & 15;       // A-row / C-col within tile
    const int q   = l >> 4;       // k-block selector
    const int r0  = blockIdx.x * ROWS_;
    const int col = 16 * w + c;   // this lane's output unit (0..63)

    // zero both h buffers (h0 = 0)
    for (int i = tid; i < 2 * ROWS_ * HSS; i += 256)
        ((half_t*)hs)[i] = (half_t)0.0f;

    // ---- B fragments: lane l holds B[k=32*cc+8q+i][n=col], fp16 ----
    h8 buz[2], bur[2], buh[2];
    #pragma unroll
    for (int cc = 0; cc < 2; ++cc) {
        #pragma unroll
        for (int i = 0; i < 8; ++i) {
            const int k = 32 * cc + 8 * q + i;
            buz[cc][i] = (half_t)U[k * 192 +       col];
            bur[cc][i] = (half_t)U[k * 192 +  64 + col];
            buh[cc][i] = (half_t)U[k * 192 + 128 + col];
        }
    }
    // x-projection chunk: K=32 with rows 16..31 zeroed (F=16)
    h8 bwz, bwr, bwh;
    #pragma unroll
    for (int i = 0; i < 8; ++i) {
        const int k = 8 * q + i;
        const bool real = (q < 2);
        bwz[i] = real ? (half_t)W[k * 192 +       col] : (half_t)0.0f;
        bwr[i] = real ? (half_t)W[k * 192 +  64 + col] : (half_t)0.0f;
        bwh[i] = real ? (half_t)W[k * 192 + 128 + col] : (half_t)0.0f;
    }
    // biases (b is [2,192]) — folded into MFMA C-init
    const float bz  = b[col]       + b[192 + col];   // bi_z + br_z
    const float br_ = b[64 + col]  + b[256 + col];   // bi_r + br_r
    const float bxh = b[128 + col];                  // bi_h (x-part)
    const float brh = b[320 + col];                  // br_h (rec-part)

    __syncthreads();   // hs zeroed

    float hold[4] = {0.f, 0.f, 0.f, 0.f};   // h for rows m=4q+i, unit col

    // x: lane reads row (r0+c), features 8*(q&1)..+7. Lanes q>=2 duplicate
    // q-2's addresses; their A values hit zeroed B rows — harmless.
    const float* xrow = x + (size_t)(r0 + c) * (T_ * F_) + 8 * (q & 1);
    float4 xfa = *(const float4*)(xrow);
    float4 xfb = *(const float4*)(xrow + 4);

    for (int t = 0; t < T_; ++t) {
        const int nb = t & 1;

        // A x-fragment from prefetched registers
        h8 ax;
        ax[0] = (half_t)xfa.x; ax[1] = (half_t)xfa.y;
        ax[2] = (half_t)xfa.z; ax[3] = (half_t)xfa.w;
        ax[4] = (half_t)xfb.x; ax[5] = (half_t)xfb.y;
        ax[6] = (half_t)xfb.z; ax[7] = (half_t)xfb.w;

        // prefetch next step's x (clamped at the end; value unused at t=T-1)
        const int tn = (t + 1 < T_) ? (t + 1) : t;
        const float4 nxa = *(const float4*)(xrow + tn * F_);
        const float4 nxb = *(const float4*)(xrow + tn * F_ + 4);

        // A h-fragments: row c, k = 8q (+32)
        const half_t* hrow = &hs[nb][c][0];
        const h8 ah0 = *(const h8*)(hrow + 8 * q);
        const h8 ah1 = *(const h8*)(hrow + 32 + 8 * q);

        f32x4 cz  = {bz,  bz,  bz,  bz };
        f32x4 cr  = {br_, br_, br_, br_};
        f32x4 crh = {brh, brh, brh, brh};
        f32x4 cxh = {bxh, bxh, bxh, bxh};
        cz  = __builtin_amdgcn_mfma_f32_16x16x32_f16(ax,  bwz,    cz,  0, 0, 0);
        cr  = __builtin_amdgcn_mfma_f32_16x16x32_f16(ax,  bwr,    cr,  0, 0, 0);
        cxh = __builtin_amdgcn_mfma_f32_16x16x32_f16(ax,  bwh,    cxh, 0, 0, 0);
        cz  = __builtin_amdgcn_mfma_f32_16x16x32_f16(ah0, buz[0], cz,  0, 0, 0);
        cr  = __builtin_amdgcn_mfma_f32_16x16x32_f16(ah0, bur[0], cr,  0, 0, 0);
        crh = __builtin_amdgcn_mfma_f32_16x16x32_f16(ah0, buh[0], crh, 0, 0, 0);
        cz  = __builtin_amdgcn_mfma_f32_16x16x32_f16(ah1, buz[1], cz,  0, 0, 0);
        cr  = __builtin_amdgcn_mfma_f32_16x16x32_f16(ah1, bur[1], cr,  0, 0, 0);
        crh = __builtin_amdgcn_mfma_f32_16x16x32_f16(ah1, buh[1], crh, 0, 0, 0);

        // gates for rows m = 4q+i; publish fp16 h to the other buffer
        half_t* wrp = &hs[nb ^ 1][0][0] + col;
        #pragma unroll
        for (int i = 0; i < 4; ++i) {
            const float z  = sigm(cz[i]);
            const float r  = sigm(cr[i]);
            const float hh = tanh_fast(fmaf(r, crh[i], cxh[i]));
            hold[i] = fmaf(z, hold[i] - hh, hh);
            wrp[(4 * q + i) * HSS] = (half_t)hold[i];
        }

        xfa = nxa; xfb = nxb;
        __syncthreads();   // all 16x64 h values published for step t+1
    }

    // ---- head: y = relu(h @ w1 + b1); BN(inference); out = y @ w2 + b2 ----
    #pragma unroll
    for (int i = 0; i < 4; ++i)
        hf[4 * q + i][col] = hold[i];
    __syncthreads();

    const int j = l;                 // head unit 0..63; wave w -> rows 4w..4w+3
    float y0 = b1[j], y1 = y0, y2 = y0, y3 = y0;
    #pragma unroll 8
    for (int k = 0; k < H_; ++k) {
        const float wk = w1[k * 64 + j];
        y0 = fmaf(hf[4 * w + 0][k], wk, y0);
        y1 = fmaf(hf[4 * w + 1][k], wk, y1);
        y2 = fmaf(hf[4 * w + 2][k], wk, y2);
        y3 = fmaf(hf[4 * w + 3][k], wk, y3);
    }
    const float sc = rsqrtf(mvar[j] + 1e-3f) * gamma_[j];
    const float mm = mmean[j], bt = beta_[j], v2 = w2[j];
    float yy[4] = {y0, y1, y2, y3};
    #pragma unroll
    for (int ri = 0; ri < 4; ++ri) {
        float yv = fmaxf(yy[ri], 0.0f);
        yv = (yv - mm) * sc + bt;
        float acc = yv * v2;
        #pragma unroll
        for (int off = 32; off > 0; off >>= 1)
            acc += __shfl_down(acc, off, 64);
        if (l == 0) out[r0 + 4 * w + ri] = acc + b2[0];
    }
}

extern "C" void kernel_launch(void* const* d_in, const int* in_sizes, int n_in,
                              void* d_out, int out_size, void* d_ws, size_t ws_size,
                              hipStream_t stream) {
    const float* x      = (const float*)d_in[0];
    const float* W      = (const float*)d_in[1];
    const float* U      = (const float*)d_in[2];
    const float* b      = (const float*)d_in[3];
    const float* w1     = (const float*)d_in[4];
    const float* b1     = (const float*)d_in[5];
    const float* gamma_ = (const float*)d_in[6];
    const float* beta_  = (const float*)d_in[7];
    const float* mmean  = (const float*)d_in[8];
    const float* mvar   = (const float*)d_in[9];
    const float* w2     = (const float*)d_in[10];
    const float* b2     = (const float*)d_in[11];
    float* out = (float*)d_out;

    const int B = in_sizes[0] / (T_ * F_);   // 1024
    gru_fused<<<B / ROWS_, 256, 0, stream>>>(x, W, U, b, w1, b1, gamma_, beta_,
                                             mmean, mvar, w2, b2, out);
}